// Round 3
// baseline (134.055 us; speedup 1.0000x reference)
//
#include <hip/hip_runtime.h>
#include <hip/hip_cooperative_groups.h>
#include <math.h>

namespace cg = cooperative_groups;

#define LN_EPS 1e-5f
// 1/(3*sqrt(32))
#define KSCALE 0.058925565098878960f

// ws layout (floats):
//   part_KV  [64][1024]  ([b][m*32+d])   offset 0
//   part_KK  [64][1024]  ([b][d*32+e])   offset 65536
//   part_QQ  [64][1024]  ([b][d*32+e])   offset 131072
//   part_Ksum[64][32]                    offset 196608
#define WS_KV 0
#define WS_KK 65536
#define WS_QQ 131072
#define WS_KS 196608

__device__ __forceinline__ float ln_row(float x) {
    float m = x;
    #pragma unroll
    for (int off = 16; off > 0; off >>= 1) m += __shfl_xor(m, off, 32);
    m *= (1.0f / 32.0f);
    float c = x - m;
    float v = c * c;
    #pragma unroll
    for (int off = 16; off > 0; off >>= 1) v += __shfl_xor(v, off, 32);
    v *= (1.0f / 32.0f);
    return c * rsqrtf(v + LN_EPS);
}

// One cooperative kernel. grid=512 x 256 threads, 2 blocks/CU co-resident.
// Phase A (blocks 0..63): b = h*8 + chunk; LN+stage 64 rows of K,V,Q in LDS;
//   each thread owns (d = grp + 8j, e = lane) cells and loops ALL 64 s
//   (round-1 proven ownership — no inter-group race); per-block ws slices,
//   so no atomics and no zero-init.
// grid.sync()
// Phase B (all 512 blocks): b = h*64 + lb; sum 8 chunk partials into padded
//   LDS; per-l-row finalize (one 32-lane group per row, 8 rows/block).
__global__ __launch_bounds__(256, 2) void fused_attn(
    const float* __restrict__ q_in, const float* __restrict__ k_in,
    const float* __restrict__ v_in, const float* __restrict__ key_len,
    float* __restrict__ ws, float* __restrict__ out)
{
    __shared__ float sK[64 * 32];
    __shared__ float sV[64 * 32];
    __shared__ float sQ[64 * 32];
    __shared__ float red[256];
    // stride-33 padding: row reads X[lane*33+e] hit bank (lane+e)%32 -> conflict-free
    __shared__ float KVs[32 * 33];
    __shared__ float KKs[32 * 33];
    __shared__ float QQs[32 * 33];
    __shared__ float Ksum_s[32];
    __shared__ float qsh[8][32];
    __shared__ float ksh[8][32];

    cg::grid_group grid = cg::this_grid();
    const int b = blockIdx.x;
    const int t = threadIdx.x;
    const int lane = t & 31;
    const int grp = t >> 5;

    if (b < 64) {
        const int h = b >> 3;
        const int s0 = (b & 7) * 64;

        // ---- stage + LN (each 32-lane group handles 8 rows) ----
        float ksum_acc = 0.0f;
        #pragma unroll
        for (int i = 0; i < 8; ++i) {
            int r = grp * 8 + i;            // local row 0..63
            int s = s0 + r;
            int g = (s * 8 + h) * 32 + lane;
            float kn = ln_row(k_in[g]) * (KSCALE * key_len[s]);
            sK[r * 32 + lane] = kn;
            ksum_acc += kn;
            sV[r * 32 + lane] = v_in[g];
            sQ[r * 32 + lane] = ln_row(q_in[g]);
        }
        red[t] = ksum_acc;
        __syncthreads();
        if (t < 32) {
            float a = 0.0f;
            #pragma unroll
            for (int g2 = 0; g2 < 8; ++g2) a += red[g2 * 32 + t];
            ws[WS_KS + b * 32 + t] = a;
        }

        // ---- Gram accumulation: thread owns (d = grp + 8j, e = lane), all s ----
        float kv[4] = {0, 0, 0, 0};
        float kk[4] = {0, 0, 0, 0};
        float qq[4] = {0, 0, 0, 0};
        #pragma unroll 4
        for (int s = 0; s < 64; ++s) {
            float ke = sK[s * 32 + lane];
            float ve = sV[s * 32 + lane];
            float qe = sQ[s * 32 + lane];
            #pragma unroll
            for (int j = 0; j < 4; ++j) {
                int d = grp + j * 8;
                float kd = sK[s * 32 + d];   // 2-addr broadcast per wave: free
                float qd = sQ[s * 32 + d];
                kv[j] += kd * ve;
                kk[j] += kd * ke;
                qq[j] += qd * qe;
            }
        }
        float* pKV = ws + WS_KV + b * 1024;
        float* pKK = ws + WS_KK + b * 1024;
        float* pQQ = ws + WS_QQ + b * 1024;
        #pragma unroll
        for (int j = 0; j < 4; ++j) {
            int d = grp + j * 8;
            pKV[lane * 32 + d] = kv[j];      // [m][d]
            pKK[d * 32 + lane] = kk[j];      // [d][e]
            pQQ[d * 32 + lane] = qq[j];      // [d][e]
        }
        __threadfence();
    }

    grid.sync();

    // ---------------- Phase B: finalize ----------------
    const int h = b >> 6;
    const int lb = b & 63;
    const int l = lb * 8 + grp;

    for (int i = t; i < 1024; i += 256) {
        int base = h * 8 * 1024 + i;
        float skv = 0.f, skk = 0.f, sqq = 0.f;
        #pragma unroll
        for (int c = 0; c < 8; ++c) {
            skv += ws[WS_KV + base + c * 1024];
            skk += ws[WS_KK + base + c * 1024];
            sqq += ws[WS_QQ + base + c * 1024];
        }
        int r = i >> 5, cc = i & 31;
        KVs[r * 33 + cc] = skv;
        KKs[r * 33 + cc] = skk;
        QQs[r * 33 + cc] = sqq;
    }
    if (t < 32) {
        float a = 0.0f;
        #pragma unroll
        for (int c = 0; c < 8; ++c) a += ws[WS_KS + (h * 8 + c) * 32 + t];
        Ksum_s[t] = a;
    }

    const int gidx = (l * 8 + h) * 32 + lane;
    float qd = ln_row(q_in[gidx]);
    float kd = ln_row(k_in[gidx]) * (KSCALE * key_len[l]);
    float vm = v_in[gidx];
    qsh[grp][lane] = qd;
    ksh[grp][lane] = kd;
    __syncthreads();

    float s1 = 0.f, s2 = 0.f, o1 = 0.f;
    #pragma unroll 8
    for (int e = 0; e < 32; ++e) {
        float qe = qsh[grp][e];
        s1 += KKs[lane * 33 + e] * qe;           // (KK q)[d=lane]
        s2 += QQs[lane * 33 + e] * ksh[grp][e];  // (QQ k)[d=lane]
        o1 += KVs[lane * 33 + e] * qe;           // order1[m=lane]
    }
    float normp = qd * Ksum_s[lane] + 0.5f * qd * s1;
    float kq2p = kd * s2;
    #pragma unroll
    for (int off = 16; off > 0; off >>= 1) {
        normp += __shfl_xor(normp, off, 32);
        kq2p  += __shfl_xor(kq2p, off, 32);
    }
    out[gidx] = (o1 + 0.5f * kq2p * vm) / normp;
}

extern "C" void kernel_launch(void* const* d_in, const int* in_sizes, int n_in,
                              void* d_out, int out_size, void* d_ws, size_t ws_size,
                              hipStream_t stream) {
    const float* q_in   = (const float*)d_in[0];
    const float* k_in   = (const float*)d_in[1];
    const float* v_in   = (const float*)d_in[2];
    // d_in[3] attn_mask (unused), d_in[4] query_lengths (unused)
    const float* key_len = (const float*)d_in[5];
    float* ws  = (float*)d_ws;
    float* out = (float*)d_out;

    void* args[] = {(void*)&q_in, (void*)&k_in, (void*)&v_in,
                    (void*)&key_len, (void*)&ws, (void*)&out};
    hipLaunchCooperativeKernel(reinterpret_cast<void*>(fused_attn),
                               dim3(512), dim3(256), args, 0, stream);
}